// Round 3
// baseline (465.712 us; speedup 1.0000x reference)
//
#include <hip/hip_runtime.h>
#include <math.h>

#define N_NODES 100000
#define N_EDGES 1600000

static inline size_t align256(size_t x) { return (x + 255) & ~((size_t)255); }

constexpr int SCAN_T = 1024;
constexpr int NCHUNK = (N_NODES + SCAN_T - 1) / SCAN_T;  // 98

// ---------------- CSR build (atomic-minimized) ----------------
// pass1: returning atomic doubles as histogram AND per-edge slot index.

__global__ void pass1_kernel(const int* __restrict__ dst, int* __restrict__ cnt,
                             int* __restrict__ pos) {
  int i = blockIdx.x * blockDim.x + threadIdx.x;
  if (i < N_EDGES / 4) {
    int4 d = ((const int4*)dst)[i];
    int4 p;
    p.x = atomicAdd(&cnt[d.x], 1);
    p.y = atomicAdd(&cnt[d.y], 1);
    p.z = atomicAdd(&cnt[d.z], 1);
    p.w = atomicAdd(&cnt[d.w], 1);
    ((int4*)pos)[i] = p;
  }
}

__global__ __launch_bounds__(1024) void scan1_kernel(const int* __restrict__ cnt,
                                                     int* __restrict__ rowptr,
                                                     int* __restrict__ blocksum,
                                                     float* __restrict__ invdeg) {
  __shared__ int s[SCAN_T];
  int t = threadIdx.x;
  int i = blockIdx.x * SCAN_T + t;
  int v = (i < N_NODES) ? cnt[i] : 0;
  s[t] = v;
  __syncthreads();
  for (int off = 1; off < SCAN_T; off <<= 1) {
    int add = (t >= off) ? s[t - off] : 0;
    __syncthreads();
    s[t] += add;
    __syncthreads();
  }
  if (i < N_NODES) {
    rowptr[i] = s[t] - v;  // exclusive (pre block offset)
    invdeg[i] = 1.0f / (float)((v > 0) ? v : 1);
  }
  if (t == SCAN_T - 1) blocksum[blockIdx.x] = s[t];
}

__global__ void scan2_kernel(int* __restrict__ blocksum, int nb) {
  __shared__ int s[128];
  int t = threadIdx.x;  // 128 threads
  int v = (t < nb) ? blocksum[t] : 0;
  s[t] = v;
  __syncthreads();
  for (int off = 1; off < 128; off <<= 1) {
    int add = (t >= off) ? s[t - off] : 0;
    __syncthreads();
    s[t] += add;
    __syncthreads();
  }
  if (t < nb) blocksum[t] = s[t] - v;  // exclusive block offsets
}

__global__ __launch_bounds__(1024) void scan3_kernel(int* __restrict__ rowptr,
                                                     const int* __restrict__ blocksum) {
  int i = blockIdx.x * SCAN_T + threadIdx.x;
  if (i < N_NODES) rowptr[i] += blocksum[blockIdx.x];
}

// pass2: no atomics — position already known.
__global__ void pass2_kernel(const int* __restrict__ src, const int* __restrict__ dst,
                             const int* __restrict__ pos, const int* __restrict__ rowptr,
                             int* __restrict__ col) {
  int i = blockIdx.x * blockDim.x + threadIdx.x;
  if (i < N_EDGES / 4) {
    int4 s4 = ((const int4*)src)[i];
    int4 d4 = ((const int4*)dst)[i];
    int4 p4 = ((const int4*)pos)[i];
    col[rowptr[d4.x] + p4.x] = s4.x;
    col[rowptr[d4.y] + p4.y] = s4.y;
    col[rowptr[d4.z] + p4.z] = s4.z;
    col[rowptr[d4.w] + p4.w] = s4.w;
  }
}

// ---------------- fused SAGEConv + BN + ReLU (layers 0 and 1) ----------------
// block = 512 threads = 8 waves. Each wave processes 8 nodes per round.
// If sums != nullptr, also accumulates sums[ch] += Σ_nodes out[ch] (for the
// collapsed layer-2 node-mean), deleting the separate reduce pass.

__global__ __launch_bounds__(512) void layer_kernel(
    const float* __restrict__ hin, const int* __restrict__ rowptr,
    const int* __restrict__ cnt, const int* __restrict__ col,
    const float* __restrict__ wl, const float* __restrict__ bl,
    const float* __restrict__ wr,
    const float* __restrict__ g, const float* __restrict__ be,
    const float* __restrict__ m, const float* __restrict__ v,
    float* __restrict__ hout, float* __restrict__ sums) {
  // wwS[k2*64+j] = {wl[j][2k2], wr[j][2k2], wl[j][2k2+1], wr[j][2k2+1]}
  __shared__ float4 wwS[2048];            // 32 KB
  // exS[wave][node][k2] = {aggr[2k2], own[2k2], aggr[2k2+1], own[2k2+1]}
  __shared__ float4 exS[8][8][33];        // 33 KB (pad 33 for banks)
  __shared__ float scaleS[64], shiftS[64], biasS[64];
  __shared__ float redS[8][64];

  const int tid = threadIdx.x;
  for (int idx = tid; idx < 2048; idx += 512) {
    int k2 = idx >> 6, j = idx & 63;
    wwS[idx] = make_float4(wl[j * 64 + 2 * k2], wr[j * 64 + 2 * k2],
                           wl[j * 64 + 2 * k2 + 1], wr[j * 64 + 2 * k2 + 1]);
  }
  if (tid < 64) {
    float sc = rsqrtf(v[tid] + 1e-5f) * g[tid];
    scaleS[tid] = sc;
    shiftS[tid] = be[tid] - m[tid] * sc;
    biasS[tid] = bl[tid];
  }
  __syncthreads();

  const int lane = tid & 63;
  const int wv = tid >> 6;
  const int slot = lane >> 4;   // 0..3 node slot
  const int c = lane & 15;      // channel quad
  const int c4 = c * 4;
  const int wid = blockIdx.x * 8 + wv;
  const int nwaves = gridDim.x * 8;
  float accsum = 0.0f;

  for (int gidx = wid; gidx < (N_NODES / 8); gidx += nwaves) {
    const int nbase = gidx * 8;

    // ---- phase 1: gather 8 nodes ----
#pragma unroll
    for (int sub = 0; sub < 2; ++sub) {
      const int node = nbase + sub * 4 + slot;
      const float4 own = *(const float4*)(hin + (size_t)node * 64 + c4);
      const int start = rowptr[node];
      const int deg = cnt[node];
      const int* cp = col + start;
      float ax = 0.f, ay = 0.f, az = 0.f, aw = 0.f;
      int e = 0;
      for (; e + 4 <= deg; e += 4) {
        int s0 = cp[e], s1 = cp[e + 1], s2 = cp[e + 2], s3 = cp[e + 3];
        float4 v0 = *(const float4*)(hin + (size_t)s0 * 64 + c4);
        float4 v1 = *(const float4*)(hin + (size_t)s1 * 64 + c4);
        float4 v2 = *(const float4*)(hin + (size_t)s2 * 64 + c4);
        float4 v3 = *(const float4*)(hin + (size_t)s3 * 64 + c4);
        ax += (v0.x + v1.x) + (v2.x + v3.x);
        ay += (v0.y + v1.y) + (v2.y + v3.y);
        az += (v0.z + v1.z) + (v2.z + v3.z);
        aw += (v0.w + v1.w) + (v2.w + v3.w);
      }
      for (; e < deg; ++e) {
        float4 v0 = *(const float4*)(hin + (size_t)cp[e] * 64 + c4);
        ax += v0.x; ay += v0.y; az += v0.z; aw += v0.w;
      }
      const float inv = (deg > 0) ? (1.0f / (float)deg) : 0.0f;
      ax *= inv; ay *= inv; az *= inv; aw *= inv;
      const int n = sub * 4 + slot;
      exS[wv][n][2 * c]     = make_float4(ax, own.x, ay, own.y);
      exS[wv][n][2 * c + 1] = make_float4(az, own.z, aw, own.w);
    }
    // same-wave produce/consume; compiler inserts lgkmcnt waits — no barrier

    // ---- phase 2: transform, lane = output channel j ----
    float out[8] = {0.f, 0.f, 0.f, 0.f, 0.f, 0.f, 0.f, 0.f};
#pragma unroll 4
    for (int k2 = 0; k2 < 32; ++k2) {
      float4 w = wwS[k2 * 64 + lane];
#pragma unroll
      for (int n = 0; n < 8; ++n) {
        float4 ao = exS[wv][n][k2];
        out[n] += w.x * ao.x + w.y * ao.y + w.z * ao.z + w.w * ao.w;
      }
    }

    const float sc = scaleS[lane], sh = shiftS[lane], bi = biasS[lane];
#pragma unroll
    for (int n = 0; n < 8; ++n) {
      float o = fmaxf((out[n] + bi) * sc + sh, 0.0f);
      accsum += o;
      hout[(size_t)(nbase + n) * 64 + lane] = o;
    }
  }

  if (sums) {
    redS[wv][lane] = accsum;
    __syncthreads();
    if (wv == 0) {
      float t = 0.f;
#pragma unroll
      for (int w = 0; w < 8; ++w) t += redS[w][lane];
      atomicAdd(&sums[lane], t);
    }
  }
}

// ---------------- edge-parallel Σ_e invdeg[dst]·h2[src] → sums[64:128] ----------------

__global__ __launch_bounds__(256) void edge_reduce_kernel(
    const float* __restrict__ h2, const int* __restrict__ src,
    const int* __restrict__ dst, const float* __restrict__ invdeg,
    float* __restrict__ sums) {
  __shared__ float4 redS[4][16];
  const int tid = threadIdx.x;
  const int lane = tid & 63, wv = tid >> 6;
  const int slot = lane >> 4;
  const int c4 = (lane & 15) * 4;
  const int gw = blockIdx.x * 4 + wv;
  const int nw = gridDim.x * 4;
  float4 acc = make_float4(0.f, 0.f, 0.f, 0.f);
  for (int e = gw * 4 + slot; e < N_EDGES; e += nw * 4) {
    int s = src[e];
    float w = invdeg[dst[e]];
    const float4 v = *(const float4*)(h2 + (size_t)s * 64 + c4);
    acc.x += w * v.x; acc.y += w * v.y; acc.z += w * v.z; acc.w += w * v.w;
  }
  // reduce across the 4 node-slots (lane bits 4,5)
  acc.x += __shfl_xor(acc.x, 16); acc.y += __shfl_xor(acc.y, 16);
  acc.z += __shfl_xor(acc.z, 16); acc.w += __shfl_xor(acc.w, 16);
  acc.x += __shfl_xor(acc.x, 32); acc.y += __shfl_xor(acc.y, 32);
  acc.z += __shfl_xor(acc.z, 32); acc.w += __shfl_xor(acc.w, 32);
  if (slot == 0) redS[wv][lane & 15] = acc;
  __syncthreads();
  if (tid < 16) {
    float4 a = redS[0][tid], b = redS[1][tid], c2 = redS[2][tid], d2 = redS[3][tid];
    atomicAdd(&sums[64 + tid * 4 + 0], a.x + b.x + c2.x + d2.x);
    atomicAdd(&sums[64 + tid * 4 + 1], a.y + b.y + c2.y + d2.y);
    atomicAdd(&sums[64 + tid * 4 + 2], a.z + b.z + c2.z + d2.z);
    atomicAdd(&sums[64 + tid * 4 + 3], a.w + b.w + c2.w + d2.w);
  }
}

// ---------------- collapsed layer 2 + classifier + sigmoid ----------------

__global__ void final_kernel(const float* __restrict__ sums,
                             const float* __restrict__ wl2, const float* __restrict__ bl2,
                             const float* __restrict__ wr2,
                             const float* __restrict__ cw1, const float* __restrict__ cb1,
                             const float* __restrict__ cw2, const float* __restrict__ cb2,
                             float* __restrict__ out) {
  __shared__ float maS[64], mhS[64], m3S[64], tS[64];
  int j = threadIdx.x;  // 64 threads
  float invN = 1.0f / (float)N_NODES;
  mhS[j] = sums[j] * invN;        // mean of h2
  maS[j] = sums[64 + j] * invN;   // mean of aggr3
  __syncthreads();
  float acc = bl2[j];
#pragma unroll
  for (int k = 0; k < 64; ++k)
    acc += wl2[j * 64 + k] * maS[k] + wr2[j * 64 + k] * mhS[k];
  m3S[j] = acc;
  __syncthreads();
  float c = cb1[j];
#pragma unroll
  for (int k = 0; k < 64; ++k) c += cw1[j * 64 + k] * m3S[k];
  tS[j] = fmaxf(c, 0.f);
  __syncthreads();
  float r = tS[j] * cw2[j];
#pragma unroll
  for (int off = 32; off > 0; off >>= 1) r += __shfl_down(r, off);
  if (j == 0) out[0] = 1.0f / (1.0f + expf(-(r + cb2[0])));
}

// ---------------- host launcher ----------------

extern "C" void kernel_launch(void* const* d_in, const int* in_sizes, int n_in,
                              void* d_out, int out_size, void* d_ws, size_t ws_size,
                              hipStream_t stream) {
  const float* x   = (const float*)d_in[0];
  const int* ei    = (const int*)d_in[1];
  const float* wl0 = (const float*)d_in[2];
  const float* bl0 = (const float*)d_in[3];
  const float* wr0 = (const float*)d_in[4];
  const float* wl1 = (const float*)d_in[5];
  const float* bl1 = (const float*)d_in[6];
  const float* wr1 = (const float*)d_in[7];
  const float* wl2 = (const float*)d_in[8];
  const float* bl2 = (const float*)d_in[9];
  const float* wr2 = (const float*)d_in[10];
  const float* g0  = (const float*)d_in[11];
  const float* be0 = (const float*)d_in[12];
  const float* m0  = (const float*)d_in[13];
  const float* v0  = (const float*)d_in[14];
  const float* g1  = (const float*)d_in[15];
  const float* be1 = (const float*)d_in[16];
  const float* m1  = (const float*)d_in[17];
  const float* v1  = (const float*)d_in[18];
  const float* cw1 = (const float*)d_in[19];
  const float* cb1 = (const float*)d_in[20];
  const float* cw2 = (const float*)d_in[21];
  const float* cb2 = (const float*)d_in[22];

  const int* srcp = ei;            // edge_index[0]
  const int* dstp = ei + N_EDGES;  // edge_index[1]

  char* ws = (char*)d_ws;
  size_t off = 0;
  auto alloc = [&](size_t bytes) {
    void* p = ws + off;
    off = align256(off + bytes);
    return p;
  };
  int* cnt       = (int*)alloc((size_t)N_NODES * 4);
  int* rowptr    = (int*)alloc((size_t)N_NODES * 4);
  float* invdeg  = (float*)alloc((size_t)N_NODES * 4);
  int* blocksum  = (int*)alloc(128 * 4);
  int* pos       = (int*)alloc((size_t)N_EDGES * 4);
  int* col       = (int*)alloc((size_t)N_EDGES * 4);
  float* sums    = (float*)alloc(128 * 4);
  float* h1      = (float*)alloc((size_t)N_NODES * 64 * 4);
  float* h2      = (float*)alloc((size_t)N_NODES * 64 * 4);
  (void)off; (void)ws_size; (void)in_sizes; (void)n_in; (void)out_size;

  hipMemsetAsync(cnt, 0, (size_t)N_NODES * 4, stream);
  hipMemsetAsync(sums, 0, 128 * 4, stream);

  int eg4 = (N_EDGES / 4 + 255) / 256;
  pass1_kernel<<<eg4, 256, 0, stream>>>(dstp, cnt, pos);
  scan1_kernel<<<NCHUNK, SCAN_T, 0, stream>>>(cnt, rowptr, blocksum, invdeg);
  scan2_kernel<<<1, 128, 0, stream>>>(blocksum, NCHUNK);
  scan3_kernel<<<NCHUNK, SCAN_T, 0, stream>>>(rowptr, blocksum);
  pass2_kernel<<<eg4, 256, 0, stream>>>(srcp, dstp, pos, rowptr, col);

  layer_kernel<<<512, 512, 0, stream>>>(x, rowptr, cnt, col, wl0, bl0, wr0,
                                        g0, be0, m0, v0, h1, nullptr);
  layer_kernel<<<512, 512, 0, stream>>>(h1, rowptr, cnt, col, wl1, bl1, wr1,
                                        g1, be1, m1, v1, h2, sums);
  edge_reduce_kernel<<<1024, 256, 0, stream>>>(h2, srcp, dstp, invdeg, sums);
  final_kernel<<<1, 64, 0, stream>>>(sums, wl2, bl2, wr2, cw1, cb1, cw2, cb2,
                                     (float*)d_out);
}

// Round 4
// 370.077 us; speedup vs baseline: 1.2584x; 1.2584x over previous
//
#include <hip/hip_runtime.h>
#include <math.h>

#define N_NODES 100000
#define N_EDGES 1600000

static inline size_t align256(size_t x) { return (x + 255) & ~((size_t)255); }

constexpr int SCAN_T = 1024;
constexpr int NCHUNK = (N_NODES + SCAN_T - 1) / SCAN_T;  // 98

// ---------------- CSR build (atomic-minimized) ----------------
// pass1: returning atomic doubles as histogram AND per-edge slot index.

__global__ void pass1_kernel(const int* __restrict__ dst, int* __restrict__ cnt,
                             int* __restrict__ pos) {
  int i = blockIdx.x * blockDim.x + threadIdx.x;
  if (i < N_EDGES / 4) {
    int4 d = ((const int4*)dst)[i];
    int4 p;
    p.x = atomicAdd(&cnt[d.x], 1);
    p.y = atomicAdd(&cnt[d.y], 1);
    p.z = atomicAdd(&cnt[d.z], 1);
    p.w = atomicAdd(&cnt[d.w], 1);
    ((int4*)pos)[i] = p;
  }
}

__global__ __launch_bounds__(1024) void scan1_kernel(const int* __restrict__ cnt,
                                                     int* __restrict__ rowptr,
                                                     int* __restrict__ blocksum,
                                                     float* __restrict__ invdeg) {
  __shared__ int s[SCAN_T];
  int t = threadIdx.x;
  int i = blockIdx.x * SCAN_T + t;
  int v = (i < N_NODES) ? cnt[i] : 0;
  s[t] = v;
  __syncthreads();
  for (int off = 1; off < SCAN_T; off <<= 1) {
    int add = (t >= off) ? s[t - off] : 0;
    __syncthreads();
    s[t] += add;
    __syncthreads();
  }
  if (i < N_NODES) {
    rowptr[i] = s[t] - v;  // exclusive (pre block offset)
    invdeg[i] = 1.0f / (float)((v > 0) ? v : 1);
  }
  if (t == SCAN_T - 1) blocksum[blockIdx.x] = s[t];
}

__global__ void scan2_kernel(int* __restrict__ blocksum, int nb) {
  __shared__ int s[128];
  int t = threadIdx.x;  // 128 threads
  int v = (t < nb) ? blocksum[t] : 0;
  s[t] = v;
  __syncthreads();
  for (int off = 1; off < 128; off <<= 1) {
    int add = (t >= off) ? s[t - off] : 0;
    __syncthreads();
    s[t] += add;
    __syncthreads();
  }
  if (t < nb) blocksum[t] = s[t] - v;  // exclusive block offsets
}

__global__ __launch_bounds__(1024) void scan3_kernel(int* __restrict__ rowptr,
                                                     const int* __restrict__ blocksum) {
  int i = blockIdx.x * SCAN_T + threadIdx.x;
  if (i < N_NODES) rowptr[i] += blocksum[blockIdx.x];
}

// pass2: col scatter (no atomics — position known) + coef[src] += invdeg[dst].
__global__ void pass2_kernel(const int* __restrict__ src, const int* __restrict__ dst,
                             const int* __restrict__ pos, const int* __restrict__ rowptr,
                             const float* __restrict__ invdeg,
                             int* __restrict__ col, float* __restrict__ coef) {
  int i = blockIdx.x * blockDim.x + threadIdx.x;
  if (i < N_EDGES / 4) {
    int4 s4 = ((const int4*)src)[i];
    int4 d4 = ((const int4*)dst)[i];
    int4 p4 = ((const int4*)pos)[i];
    col[rowptr[d4.x] + p4.x] = s4.x;
    col[rowptr[d4.y] + p4.y] = s4.y;
    col[rowptr[d4.z] + p4.z] = s4.z;
    col[rowptr[d4.w] + p4.w] = s4.w;
    atomicAdd(&coef[s4.x], invdeg[d4.x]);
    atomicAdd(&coef[s4.y], invdeg[d4.y]);
    atomicAdd(&coef[s4.z], invdeg[d4.z]);
    atomicAdd(&coef[s4.w], invdeg[d4.w]);
  }
}

// ---------------- fused SAGEConv + BN + ReLU (layers 0 and 1) ----------------
// block = 512 threads = 8 waves. Each wave processes 8 nodes per round.
// WRITE_OUT: store h to hout (layer 0).
// DO_SUMS:   accumulate sums[j]=Σ_nodes h[j], sums[64+j]=Σ_nodes coef[node]*h[j]
//            (collapsed layer 2) — layer 1 never materializes h2.

template <bool WRITE_OUT, bool DO_SUMS>
__global__ __launch_bounds__(512) void layer_kernel(
    const float* __restrict__ hin, const int* __restrict__ rowptr,
    const int* __restrict__ cnt, const int* __restrict__ col,
    const float* __restrict__ wl, const float* __restrict__ bl,
    const float* __restrict__ wr,
    const float* __restrict__ g, const float* __restrict__ be,
    const float* __restrict__ m, const float* __restrict__ v,
    float* __restrict__ hout, const float* __restrict__ coef,
    float* __restrict__ sums) {
  // wwS[k2*64+j] = {wl[j][2k2], wr[j][2k2], wl[j][2k2+1], wr[j][2k2+1]}
  __shared__ float4 wwS[2048];            // 32 KB
  // exS[wave][node][k2] = {aggr[2k2], own[2k2], aggr[2k2+1], own[2k2+1]}
  __shared__ float4 exS[8][8][33];        // 33 KB (pad 33 for banks)
  __shared__ float scaleS[64], shiftS[64], biasS[64];
  __shared__ float redS[8][128];

  const int tid = threadIdx.x;
  for (int idx = tid; idx < 2048; idx += 512) {
    int k2 = idx >> 6, j = idx & 63;
    wwS[idx] = make_float4(wl[j * 64 + 2 * k2], wr[j * 64 + 2 * k2],
                           wl[j * 64 + 2 * k2 + 1], wr[j * 64 + 2 * k2 + 1]);
  }
  if (tid < 64) {
    float sc = rsqrtf(v[tid] + 1e-5f) * g[tid];
    scaleS[tid] = sc;
    shiftS[tid] = be[tid] - m[tid] * sc;
    biasS[tid] = bl[tid];
  }
  __syncthreads();

  const int lane = tid & 63;
  const int wv = tid >> 6;
  const int slot = lane >> 4;   // 0..3 node slot
  const int c = lane & 15;      // channel quad
  const int c4 = c * 4;
  const int wid = blockIdx.x * 8 + wv;
  const int nwaves = gridDim.x * 8;
  float accsum = 0.0f, accsum2 = 0.0f;

  for (int gidx = wid; gidx < (N_NODES / 8); gidx += nwaves) {
    const int nbase = gidx * 8;

    // ---- phase 1: gather 8 nodes ----
#pragma unroll
    for (int sub = 0; sub < 2; ++sub) {
      const int node = nbase + sub * 4 + slot;
      const float4 own = *(const float4*)(hin + (size_t)node * 64 + c4);
      const int start = rowptr[node];
      const int deg = cnt[node];
      const int* cp = col + start;
      float ax = 0.f, ay = 0.f, az = 0.f, aw = 0.f;
      int e = 0;
      for (; e + 4 <= deg; e += 4) {
        int s0 = cp[e], s1 = cp[e + 1], s2 = cp[e + 2], s3 = cp[e + 3];
        float4 v0 = *(const float4*)(hin + (size_t)s0 * 64 + c4);
        float4 v1 = *(const float4*)(hin + (size_t)s1 * 64 + c4);
        float4 v2 = *(const float4*)(hin + (size_t)s2 * 64 + c4);
        float4 v3 = *(const float4*)(hin + (size_t)s3 * 64 + c4);
        ax += (v0.x + v1.x) + (v2.x + v3.x);
        ay += (v0.y + v1.y) + (v2.y + v3.y);
        az += (v0.z + v1.z) + (v2.z + v3.z);
        aw += (v0.w + v1.w) + (v2.w + v3.w);
      }
      for (; e < deg; ++e) {
        float4 v0 = *(const float4*)(hin + (size_t)cp[e] * 64 + c4);
        ax += v0.x; ay += v0.y; az += v0.z; aw += v0.w;
      }
      const float inv = (deg > 0) ? (1.0f / (float)deg) : 0.0f;
      ax *= inv; ay *= inv; az *= inv; aw *= inv;
      const int n = sub * 4 + slot;
      exS[wv][n][2 * c]     = make_float4(ax, own.x, ay, own.y);
      exS[wv][n][2 * c + 1] = make_float4(az, own.z, aw, own.w);
    }
    // same-wave produce/consume; compiler inserts lgkmcnt waits — no barrier

    // ---- phase 2: transform, lane = output channel j ----
    float out[8] = {0.f, 0.f, 0.f, 0.f, 0.f, 0.f, 0.f, 0.f};
#pragma unroll 4
    for (int k2 = 0; k2 < 32; ++k2) {
      float4 w = wwS[k2 * 64 + lane];
#pragma unroll
      for (int n = 0; n < 8; ++n) {
        float4 ao = exS[wv][n][k2];
        out[n] += w.x * ao.x + w.y * ao.y + w.z * ao.z + w.w * ao.w;
      }
    }

    const float sc = scaleS[lane], sh = shiftS[lane], bi = biasS[lane];
#pragma unroll
    for (int n = 0; n < 8; ++n) {
      float o = fmaxf((out[n] + bi) * sc + sh, 0.0f);
      if (DO_SUMS) {
        accsum += o;
        accsum2 += coef[nbase + n] * o;
      }
      if (WRITE_OUT) hout[(size_t)(nbase + n) * 64 + lane] = o;
    }
  }

  if (DO_SUMS) {
    redS[wv][lane] = accsum;
    redS[wv][64 + lane] = accsum2;
    __syncthreads();
    if (wv == 0) {
      float t0 = 0.f, t1 = 0.f;
#pragma unroll
      for (int w = 0; w < 8; ++w) {
        t0 += redS[w][lane];
        t1 += redS[w][64 + lane];
      }
      atomicAdd(&sums[lane], t0);
      atomicAdd(&sums[64 + lane], t1);
    }
  }
}

// ---------------- collapsed layer 2 + classifier + sigmoid ----------------

__global__ void final_kernel(const float* __restrict__ sums,
                             const float* __restrict__ wl2, const float* __restrict__ bl2,
                             const float* __restrict__ wr2,
                             const float* __restrict__ cw1, const float* __restrict__ cb1,
                             const float* __restrict__ cw2, const float* __restrict__ cb2,
                             float* __restrict__ out) {
  __shared__ float maS[64], mhS[64], m3S[64], tS[64];
  int j = threadIdx.x;  // 64 threads
  float invN = 1.0f / (float)N_NODES;
  mhS[j] = sums[j] * invN;        // mean of h2
  maS[j] = sums[64 + j] * invN;   // mean of aggr3
  __syncthreads();
  float acc = bl2[j];
#pragma unroll
  for (int k = 0; k < 64; ++k)
    acc += wl2[j * 64 + k] * maS[k] + wr2[j * 64 + k] * mhS[k];
  m3S[j] = acc;
  __syncthreads();
  float c = cb1[j];
#pragma unroll
  for (int k = 0; k < 64; ++k) c += cw1[j * 64 + k] * m3S[k];
  tS[j] = fmaxf(c, 0.f);
  __syncthreads();
  float r = tS[j] * cw2[j];
#pragma unroll
  for (int off = 32; off > 0; off >>= 1) r += __shfl_down(r, off);
  if (j == 0) out[0] = 1.0f / (1.0f + expf(-(r + cb2[0])));
}

// ---------------- host launcher ----------------

extern "C" void kernel_launch(void* const* d_in, const int* in_sizes, int n_in,
                              void* d_out, int out_size, void* d_ws, size_t ws_size,
                              hipStream_t stream) {
  const float* x   = (const float*)d_in[0];
  const int* ei    = (const int*)d_in[1];
  const float* wl0 = (const float*)d_in[2];
  const float* bl0 = (const float*)d_in[3];
  const float* wr0 = (const float*)d_in[4];
  const float* wl1 = (const float*)d_in[5];
  const float* bl1 = (const float*)d_in[6];
  const float* wr1 = (const float*)d_in[7];
  const float* wl2 = (const float*)d_in[8];
  const float* bl2 = (const float*)d_in[9];
  const float* wr2 = (const float*)d_in[10];
  const float* g0  = (const float*)d_in[11];
  const float* be0 = (const float*)d_in[12];
  const float* m0  = (const float*)d_in[13];
  const float* v0  = (const float*)d_in[14];
  const float* g1  = (const float*)d_in[15];
  const float* be1 = (const float*)d_in[16];
  const float* m1  = (const float*)d_in[17];
  const float* v1  = (const float*)d_in[18];
  const float* cw1 = (const float*)d_in[19];
  const float* cb1 = (const float*)d_in[20];
  const float* cw2 = (const float*)d_in[21];
  const float* cb2 = (const float*)d_in[22];

  const int* srcp = ei;            // edge_index[0]
  const int* dstp = ei + N_EDGES;  // edge_index[1]

  char* ws = (char*)d_ws;
  size_t off = 0;
  auto alloc = [&](size_t bytes) {
    void* p = ws + off;
    off = align256(off + bytes);
    return p;
  };
  int* cnt       = (int*)alloc((size_t)N_NODES * 4);
  int* rowptr    = (int*)alloc((size_t)N_NODES * 4);
  float* invdeg  = (float*)alloc((size_t)N_NODES * 4);
  float* coef    = (float*)alloc((size_t)N_NODES * 4);
  int* blocksum  = (int*)alloc(128 * 4);
  int* pos       = (int*)alloc((size_t)N_EDGES * 4);
  int* col       = (int*)alloc((size_t)N_EDGES * 4);
  float* sums    = (float*)alloc(128 * 4);
  float* h1      = (float*)alloc((size_t)N_NODES * 64 * 4);
  (void)off; (void)ws_size; (void)in_sizes; (void)n_in; (void)out_size;

  hipMemsetAsync(cnt, 0, (size_t)N_NODES * 4, stream);
  hipMemsetAsync(coef, 0, (size_t)N_NODES * 4, stream);
  hipMemsetAsync(sums, 0, 128 * 4, stream);

  int eg4 = (N_EDGES / 4 + 255) / 256;
  pass1_kernel<<<eg4, 256, 0, stream>>>(dstp, cnt, pos);
  scan1_kernel<<<NCHUNK, SCAN_T, 0, stream>>>(cnt, rowptr, blocksum, invdeg);
  scan2_kernel<<<1, 128, 0, stream>>>(blocksum, NCHUNK);
  scan3_kernel<<<NCHUNK, SCAN_T, 0, stream>>>(rowptr, blocksum);
  pass2_kernel<<<eg4, 256, 0, stream>>>(srcp, dstp, pos, rowptr, invdeg, col, coef);

  layer_kernel<true, false><<<512, 512, 0, stream>>>(
      x, rowptr, cnt, col, wl0, bl0, wr0, g0, be0, m0, v0, h1, nullptr, nullptr);
  layer_kernel<false, true><<<512, 512, 0, stream>>>(
      h1, rowptr, cnt, col, wl1, bl1, wr1, g1, be1, m1, v1, nullptr, coef, sums);
  final_kernel<<<1, 64, 0, stream>>>(sums, wl2, bl2, wr2, cw1, cb1, cw2, cb2,
                                     (float*)d_out);
}

// Round 5
// 313.403 us; speedup vs baseline: 1.4860x; 1.1808x over previous
//
#include <hip/hip_runtime.h>
#include <math.h>

#define N_NODES 100000
#define N_EDGES 1600000

static inline size_t align256(size_t x) { return (x + 255) & ~((size_t)255); }

constexpr int SCAN_T = 1024;
constexpr int NCHUNK = (N_NODES + SCAN_T - 1) / SCAN_T;  // 98

typedef _Float16 h2 __attribute__((ext_vector_type(2)));
union HU { float f; unsigned u; h2 h; };

#if __has_builtin(__builtin_amdgcn_fdot2)
__device__ inline float fdot2f(h2 a, h2 b, float c) {
  return __builtin_amdgcn_fdot2(a, b, c, false);
}
#else
__device__ inline float fdot2f(h2 a, h2 b, float c) {
  return c + (float)a.x * (float)b.x + (float)a.y * (float)b.y;
}
#endif

// ---------------- x (f32) -> h0 (fp16) ----------------

__global__ void tohalf_kernel(const float* __restrict__ in, _Float16* __restrict__ out) {
  int i = blockIdx.x * blockDim.x + threadIdx.x;
  if (i < N_NODES * 64 / 8) {
    float4 a = ((const float4*)in)[2 * i];
    float4 b = ((const float4*)in)[2 * i + 1];
    HU p0, p1, p2, p3;
    p0.h.x = (_Float16)a.x; p0.h.y = (_Float16)a.y;
    p1.h.x = (_Float16)a.z; p1.h.y = (_Float16)a.w;
    p2.h.x = (_Float16)b.x; p2.h.y = (_Float16)b.y;
    p3.h.x = (_Float16)b.z; p3.h.y = (_Float16)b.w;
    ((uint4*)out)[i] = make_uint4(p0.u, p1.u, p2.u, p3.u);
  }
}

// ---------------- CSR build (atomic-minimized) ----------------

__global__ void pass1_kernel(const int* __restrict__ dst, int* __restrict__ cnt,
                             int* __restrict__ pos) {
  int i = blockIdx.x * blockDim.x + threadIdx.x;
  if (i < N_EDGES / 4) {
    int4 d = ((const int4*)dst)[i];
    int4 p;
    p.x = atomicAdd(&cnt[d.x], 1);
    p.y = atomicAdd(&cnt[d.y], 1);
    p.z = atomicAdd(&cnt[d.z], 1);
    p.w = atomicAdd(&cnt[d.w], 1);
    ((int4*)pos)[i] = p;
  }
}

__global__ __launch_bounds__(1024) void scan1_kernel(const int* __restrict__ cnt,
                                                     int* __restrict__ rowptr,
                                                     int* __restrict__ blocksum,
                                                     float* __restrict__ invdeg) {
  __shared__ int s[SCAN_T];
  int t = threadIdx.x;
  int i = blockIdx.x * SCAN_T + t;
  int v = (i < N_NODES) ? cnt[i] : 0;
  s[t] = v;
  __syncthreads();
  for (int off = 1; off < SCAN_T; off <<= 1) {
    int add = (t >= off) ? s[t - off] : 0;
    __syncthreads();
    s[t] += add;
    __syncthreads();
  }
  if (i < N_NODES) {
    rowptr[i] = s[t] - v;  // exclusive (pre block offset)
    invdeg[i] = 1.0f / (float)((v > 0) ? v : 1);
  }
  if (t == SCAN_T - 1) blocksum[blockIdx.x] = s[t];
}

__global__ void scan2_kernel(int* __restrict__ blocksum, int nb) {
  __shared__ int s[128];
  int t = threadIdx.x;  // 128 threads
  int v = (t < nb) ? blocksum[t] : 0;
  s[t] = v;
  __syncthreads();
  for (int off = 1; off < 128; off <<= 1) {
    int add = (t >= off) ? s[t - off] : 0;
    __syncthreads();
    s[t] += add;
    __syncthreads();
  }
  if (t < nb) blocksum[t] = s[t] - v;  // exclusive block offsets
}

__global__ __launch_bounds__(1024) void scan3_kernel(int* __restrict__ rowptr,
                                                     const int* __restrict__ blocksum) {
  int i = blockIdx.x * SCAN_T + threadIdx.x;
  if (i < N_NODES) rowptr[i] += blocksum[blockIdx.x];
}

// pass2: col scatter (no atomics — position known) + coef[src] += invdeg[dst].
__global__ void pass2_kernel(const int* __restrict__ src, const int* __restrict__ dst,
                             const int* __restrict__ pos, const int* __restrict__ rowptr,
                             const float* __restrict__ invdeg,
                             int* __restrict__ col, float* __restrict__ coef) {
  int i = blockIdx.x * blockDim.x + threadIdx.x;
  if (i < N_EDGES / 4) {
    int4 s4 = ((const int4*)src)[i];
    int4 d4 = ((const int4*)dst)[i];
    int4 p4 = ((const int4*)pos)[i];
    col[rowptr[d4.x] + p4.x] = s4.x;
    col[rowptr[d4.y] + p4.y] = s4.y;
    col[rowptr[d4.z] + p4.z] = s4.z;
    col[rowptr[d4.w] + p4.w] = s4.w;
    atomicAdd(&coef[s4.x], invdeg[d4.x]);
    atomicAdd(&coef[s4.y], invdeg[d4.y]);
    atomicAdd(&coef[s4.z], invdeg[d4.z]);
    atomicAdd(&coef[s4.w], invdeg[d4.w]);
  }
}

// ---------------- fused SAGEConv + BN + ReLU (layers 0 and 1), fp16 h ----------------
// block = 512 = 8 waves; each wave does 8 nodes/round.
// phase 1: gather fp16 (v_pk_add_f16 accumulate), exchange {aggr,own} as 8 halfs/uint4
// phase 2: lane = output channel; v_dot2_f32_f16 against fp16 weights (f32 accum)

template <bool WRITE_OUT, bool DO_SUMS>
__global__ __launch_bounds__(512) void layer_kernel(
    const _Float16* __restrict__ hin, const int* __restrict__ rowptr,
    const int* __restrict__ cnt, const int* __restrict__ col,
    const float* __restrict__ wl, const float* __restrict__ bl,
    const float* __restrict__ wr,
    const float* __restrict__ g, const float* __restrict__ be,
    const float* __restrict__ m, const float* __restrict__ v,
    _Float16* __restrict__ hout, const float* __restrict__ coef,
    float* __restrict__ sums) {
  __shared__ uint4 wwS[1024];        // [k4*64+j]: {wl01,wl23,wr01,wr23} fp16 pairs, 16 KB
  __shared__ uint4 exS[8][8][17];    // [wave][node][c-group(16)+pad]: {a01,a23,o01,o23}
  __shared__ float scaleS[64], shiftS[64], biasS[64];
  __shared__ float redS[8][128];

  const int tid = threadIdx.x;
  for (int idx = tid; idx < 1024; idx += 512) {
    int k4 = idx >> 6, j = idx & 63;
    const float* pl = wl + j * 64 + k4 * 4;
    const float* pr = wr + j * 64 + k4 * 4;
    HU a0, a1, o0, o1;
    a0.h.x = (_Float16)pl[0]; a0.h.y = (_Float16)pl[1];
    a1.h.x = (_Float16)pl[2]; a1.h.y = (_Float16)pl[3];
    o0.h.x = (_Float16)pr[0]; o0.h.y = (_Float16)pr[1];
    o1.h.x = (_Float16)pr[2]; o1.h.y = (_Float16)pr[3];
    wwS[idx] = make_uint4(a0.u, a1.u, o0.u, o1.u);
  }
  if (tid < 64) {
    float sc = rsqrtf(v[tid] + 1e-5f) * g[tid];
    scaleS[tid] = sc;
    shiftS[tid] = be[tid] - m[tid] * sc;
    biasS[tid] = bl[tid];
  }
  __syncthreads();

  const int lane = tid & 63;
  const int wv = tid >> 6;
  const int slot = lane >> 4;   // 0..3 node slot
  const int c = lane & 15;      // channel quad (4 halfs = 8 B)
  const int wid = blockIdx.x * 8 + wv;
  const int nwaves = gridDim.x * 8;
  float accsum = 0.0f, accsum2 = 0.0f;

  for (int gidx = wid; gidx < (N_NODES / 8); gidx += nwaves) {
    const int nbase = gidx * 8;

    // ---- phase 1: gather 8 nodes (fp16) ----
#pragma unroll
    for (int sub = 0; sub < 2; ++sub) {
      const int node = nbase + sub * 4 + slot;
      const float2 ownraw = ((const float2*)(hin + (size_t)node * 64))[c];
      const int start = rowptr[node];
      const int deg = cnt[node];
      const int* cp = col + start;
      h2 a01 = (h2)(_Float16)0, a23 = (h2)(_Float16)0;
      int e = 0;
      for (; e + 4 <= deg; e += 4) {
        int s0 = cp[e], s1 = cp[e + 1], s2 = cp[e + 2], s3 = cp[e + 3];
        float2 r0 = ((const float2*)(hin + (size_t)s0 * 64))[c];
        float2 r1 = ((const float2*)(hin + (size_t)s1 * 64))[c];
        float2 r2 = ((const float2*)(hin + (size_t)s2 * 64))[c];
        float2 r3 = ((const float2*)(hin + (size_t)s3 * 64))[c];
        HU u;
        u.f = r0.x; a01 += u.h; u.f = r0.y; a23 += u.h;
        u.f = r1.x; a01 += u.h; u.f = r1.y; a23 += u.h;
        u.f = r2.x; a01 += u.h; u.f = r2.y; a23 += u.h;
        u.f = r3.x; a01 += u.h; u.f = r3.y; a23 += u.h;
      }
      for (; e < deg; ++e) {
        float2 r0 = ((const float2*)(hin + (size_t)cp[e] * 64))[c];
        HU u;
        u.f = r0.x; a01 += u.h; u.f = r0.y; a23 += u.h;
      }
      const _Float16 hinv = (_Float16)((deg > 0) ? (1.0f / (float)deg) : 0.0f);
      h2 vinv; vinv.x = hinv; vinv.y = hinv;
      a01 *= vinv; a23 *= vinv;
      HU wa0, wa1, wo0, wo1;
      wa0.h = a01; wa1.h = a23;
      wo0.f = ownraw.x; wo1.f = ownraw.y;
      exS[wv][sub * 4 + slot][c] = make_uint4(wa0.u, wa1.u, wo0.u, wo1.u);
    }
    // same-wave produce/consume; compiler inserts lgkmcnt waits — no barrier

    // ---- phase 2: transform, lane = output channel j ----
    float out[8] = {0.f, 0.f, 0.f, 0.f, 0.f, 0.f, 0.f, 0.f};
#pragma unroll 4
    for (int k4 = 0; k4 < 16; ++k4) {
      uint4 w4 = wwS[k4 * 64 + lane];
      HU wl01, wl23, wr01, wr23;
      wl01.u = w4.x; wl23.u = w4.y; wr01.u = w4.z; wr23.u = w4.w;
#pragma unroll
      for (int n = 0; n < 8; ++n) {
        uint4 ao = exS[wv][n][k4];
        HU a01, a23, o01, o23;
        a01.u = ao.x; a23.u = ao.y; o01.u = ao.z; o23.u = ao.w;
        float t = out[n];
        t = fdot2f(a01.h, wl01.h, t);
        t = fdot2f(a23.h, wl23.h, t);
        t = fdot2f(o01.h, wr01.h, t);
        t = fdot2f(o23.h, wr23.h, t);
        out[n] = t;
      }
    }

    const float sc = scaleS[lane], sh = shiftS[lane], bi = biasS[lane];
#pragma unroll
    for (int n = 0; n < 8; ++n) {
      float o = fmaxf((out[n] + bi) * sc + sh, 0.0f);
      if (DO_SUMS) {
        accsum += o;
        accsum2 += coef[nbase + n] * o;
      }
      if (WRITE_OUT) hout[(size_t)(nbase + n) * 64 + lane] = (_Float16)o;
    }
  }

  if (DO_SUMS) {
    redS[wv][lane] = accsum;
    redS[wv][64 + lane] = accsum2;
    __syncthreads();
    if (wv == 0) {
      float t0 = 0.f, t1 = 0.f;
#pragma unroll
      for (int w = 0; w < 8; ++w) {
        t0 += redS[w][lane];
        t1 += redS[w][64 + lane];
      }
      atomicAdd(&sums[lane], t0);
      atomicAdd(&sums[64 + lane], t1);
    }
  }
}

// ---------------- collapsed layer 2 + classifier + sigmoid ----------------

__global__ void final_kernel(const float* __restrict__ sums,
                             const float* __restrict__ wl2, const float* __restrict__ bl2,
                             const float* __restrict__ wr2,
                             const float* __restrict__ cw1, const float* __restrict__ cb1,
                             const float* __restrict__ cw2, const float* __restrict__ cb2,
                             float* __restrict__ out) {
  __shared__ float maS[64], mhS[64], m3S[64], tS[64];
  int j = threadIdx.x;  // 64 threads
  float invN = 1.0f / (float)N_NODES;
  mhS[j] = sums[j] * invN;        // mean of h2
  maS[j] = sums[64 + j] * invN;   // mean of aggr3
  __syncthreads();
  float acc = bl2[j];
#pragma unroll
  for (int k = 0; k < 64; ++k)
    acc += wl2[j * 64 + k] * maS[k] + wr2[j * 64 + k] * mhS[k];
  m3S[j] = acc;
  __syncthreads();
  float c = cb1[j];
#pragma unroll
  for (int k = 0; k < 64; ++k) c += cw1[j * 64 + k] * m3S[k];
  tS[j] = fmaxf(c, 0.f);
  __syncthreads();
  float r = tS[j] * cw2[j];
#pragma unroll
  for (int off = 32; off > 0; off >>= 1) r += __shfl_down(r, off);
  if (j == 0) out[0] = 1.0f / (1.0f + expf(-(r + cb2[0])));
}

// ---------------- host launcher ----------------

extern "C" void kernel_launch(void* const* d_in, const int* in_sizes, int n_in,
                              void* d_out, int out_size, void* d_ws, size_t ws_size,
                              hipStream_t stream) {
  const float* x   = (const float*)d_in[0];
  const int* ei    = (const int*)d_in[1];
  const float* wl0 = (const float*)d_in[2];
  const float* bl0 = (const float*)d_in[3];
  const float* wr0 = (const float*)d_in[4];
  const float* wl1 = (const float*)d_in[5];
  const float* bl1 = (const float*)d_in[6];
  const float* wr1 = (const float*)d_in[7];
  const float* wl2 = (const float*)d_in[8];
  const float* bl2 = (const float*)d_in[9];
  const float* wr2 = (const float*)d_in[10];
  const float* g0  = (const float*)d_in[11];
  const float* be0 = (const float*)d_in[12];
  const float* m0  = (const float*)d_in[13];
  const float* v0  = (const float*)d_in[14];
  const float* g1  = (const float*)d_in[15];
  const float* be1 = (const float*)d_in[16];
  const float* m1  = (const float*)d_in[17];
  const float* v1  = (const float*)d_in[18];
  const float* cw1 = (const float*)d_in[19];
  const float* cb1 = (const float*)d_in[20];
  const float* cw2 = (const float*)d_in[21];
  const float* cb2 = (const float*)d_in[22];

  const int* srcp = ei;            // edge_index[0]
  const int* dstp = ei + N_EDGES;  // edge_index[1]

  char* ws = (char*)d_ws;
  size_t off = 0;
  auto alloc = [&](size_t bytes) {
    void* p = ws + off;
    off = align256(off + bytes);
    return p;
  };
  int* cnt        = (int*)alloc((size_t)N_NODES * 4);
  int* rowptr     = (int*)alloc((size_t)N_NODES * 4);
  float* invdeg   = (float*)alloc((size_t)N_NODES * 4);
  float* coef     = (float*)alloc((size_t)N_NODES * 4);
  int* blocksum   = (int*)alloc(128 * 4);
  int* pos        = (int*)alloc((size_t)N_EDGES * 4);
  int* col        = (int*)alloc((size_t)N_EDGES * 4);
  float* sums     = (float*)alloc(128 * 4);
  _Float16* h0    = (_Float16*)alloc((size_t)N_NODES * 64 * 2);
  _Float16* h1    = (_Float16*)alloc((size_t)N_NODES * 64 * 2);
  (void)off; (void)ws_size; (void)in_sizes; (void)n_in; (void)out_size;

  hipMemsetAsync(cnt, 0, (size_t)N_NODES * 4, stream);
  hipMemsetAsync(coef, 0, (size_t)N_NODES * 4, stream);
  hipMemsetAsync(sums, 0, 128 * 4, stream);

  tohalf_kernel<<<(N_NODES * 64 / 8 + 255) / 256, 256, 0, stream>>>(x, h0);

  int eg4 = (N_EDGES / 4 + 255) / 256;
  pass1_kernel<<<eg4, 256, 0, stream>>>(dstp, cnt, pos);
  scan1_kernel<<<NCHUNK, SCAN_T, 0, stream>>>(cnt, rowptr, blocksum, invdeg);
  scan2_kernel<<<1, 128, 0, stream>>>(blocksum, NCHUNK);
  scan3_kernel<<<NCHUNK, SCAN_T, 0, stream>>>(rowptr, blocksum);
  pass2_kernel<<<eg4, 256, 0, stream>>>(srcp, dstp, pos, rowptr, invdeg, col, coef);

  layer_kernel<true, false><<<768, 512, 0, stream>>>(
      h0, rowptr, cnt, col, wl0, bl0, wr0, g0, be0, m0, v0, h1, nullptr, nullptr);
  layer_kernel<false, true><<<768, 512, 0, stream>>>(
      h1, rowptr, cnt, col, wl1, bl1, wr1, g1, be1, m1, v1, nullptr, coef, sums);
  final_kernel<<<1, 64, 0, stream>>>(sums, wl2, bl2, wr2, cw1, cb1, cw2, cb2,
                                     (float*)d_out);
}